// Round 2
// baseline (1144.732 us; speedup 1.0000x reference)
//
#include <hip/hip_runtime.h>

#define NP 16
#define D 768
#define PST 769  // odd stride: proto a shifts LDS bank by a -> scatter covers all 32 banks

// ws layout (floats):
// [0, 12288)      normalized prototypes
// [12288, 24576)  global sums accumulator
// [24576, 24592)  global counts accumulator

__global__ __launch_bounds__(64) void setup_kernel(const float* __restrict__ protos,
                                                   float* __restrict__ ws) {
    const int p = blockIdx.x;     // 0..15
    const int lane = threadIdx.x; // 0..63

    // zero this proto's slice of the global accumulators
    float* gsum = ws + 12288 + p * D;
    for (int j = lane; j < D; j += 64) gsum[j] = 0.f;
    if (lane == 0) ws[24576 + p] = 0.f;

    // row-normalize prototype p
    const float* pr = protos + p * D;
    float v[12];
    float ns = 0.f;
#pragma unroll
    for (int j = 0; j < 12; ++j) {
        v[j] = pr[lane + 64 * j];
        ns = fmaf(v[j], v[j], ns);
    }
#pragma unroll
    for (int m = 1; m < 64; m <<= 1) ns += __shfl_xor(ns, m);
    const float rn = 1.0f / sqrtf(ns);
    float* pn = ws + p * D;
#pragma unroll
    for (int j = 0; j < 12; ++j) pn[lane + 64 * j] = v[j] * rn;
}

__global__ __launch_bounds__(1024, 4) void assign_accum_kernel(
    const float* __restrict__ x, const float* __restrict__ ws,
    float* __restrict__ gsum, float* __restrict__ gcnt, int nrows) {
    __shared__ float sP[NP * D];    // 48 KB: normalized protos
    __shared__ float sS[NP * PST];  // ~48 KB: per-block segment sums (odd stride)
    __shared__ float sC[NP];

    const int tid = threadIdx.x;

    for (int i = tid; i < NP * D; i += 1024) sP[i] = ws[i];
    for (int i = tid; i < NP * PST; i += 1024) sS[i] = 0.f;
    if (tid < NP) sC[tid] = 0.f;
    __syncthreads();

    const int k = tid & 15;    // d-slice owner within a row (16 lanes/row)
    const int grp = tid >> 4;  // row-group id within block: 0..63

    const float* sPk = sP + k * 4;
    const int ntiles = (nrows + 63) >> 6;  // 64 rows per block-iteration

    for (int t = blockIdx.x; t < ntiles; t += gridDim.x) {
        const int row = (t << 6) + grp;
        const bool valid = row < nrows;
        const int rc = valid ? row : 0;

        // load this lane's 48-float slice of the row (12 x float4, stride 64 floats)
        float4 xa[12];
        const float* px = x + (size_t)rc * D + k * 4;
#pragma unroll
        for (int j = 0; j < 12; ++j) xa[j] = *reinterpret_cast<const float4*>(px + j * 64);

        // 16 partial dots + norm
        float ns = 0.f;
        float d[NP];
#pragma unroll
        for (int p = 0; p < NP; ++p) d[p] = 0.f;
#pragma unroll
        for (int j = 0; j < 12; ++j) {
            const float4 a = xa[j];
            ns = fmaf(a.x, a.x, fmaf(a.y, a.y, fmaf(a.z, a.z, fmaf(a.w, a.w, ns))));
#pragma unroll
            for (int p = 0; p < NP; ++p) {
                const float4 pv = *reinterpret_cast<const float4*>(sPk + p * D + j * 64);
                d[p] = fmaf(a.x, pv.x, fmaf(a.y, pv.y, fmaf(a.z, pv.z, fmaf(a.w, pv.w, d[p]))));
            }
        }

        // distribute-reduce across the 16 lanes: lane k ends with full dot for proto k
        float v8[8], v4[4], v2[2], vk;
        {
            const int b0 = k & 1;
#pragma unroll
            for (int i = 0; i < 8; ++i) {
                const float keep = b0 ? d[2 * i + 1] : d[2 * i];
                const float send = b0 ? d[2 * i] : d[2 * i + 1];
                v8[i] = keep + __shfl_xor(send, 1);
            }
            const int b1 = (k >> 1) & 1;
#pragma unroll
            for (int i = 0; i < 4; ++i) {
                const float keep = b1 ? v8[2 * i + 1] : v8[2 * i];
                const float send = b1 ? v8[2 * i] : v8[2 * i + 1];
                v4[i] = keep + __shfl_xor(send, 2);
            }
            const int b2 = (k >> 2) & 1;
#pragma unroll
            for (int i = 0; i < 2; ++i) {
                const float keep = b2 ? v4[2 * i + 1] : v4[2 * i];
                const float send = b2 ? v4[2 * i] : v4[2 * i + 1];
                v2[i] = keep + __shfl_xor(send, 4);
            }
            const int b3 = (k >> 3) & 1;
            {
                const float keep = b3 ? v2[1] : v2[0];
                const float send = b3 ? v2[0] : v2[1];
                vk = keep + __shfl_xor(send, 8);
            }
        }

        // row norm (all 16 lanes get full sum)
#pragma unroll
        for (int m = 1; m <= 8; m <<= 1) ns += __shfl_xor(ns, m);
        const float rn = 1.0f / sqrtf(ns);

        // argmax over the 16 lanes, first-index tie-break (matches argmin semantics)
        float bv = vk;
        int bi = k;
#pragma unroll
        for (int m = 1; m <= 8; m <<= 1) {
            const float ov = __shfl_xor(bv, m);
            const int oi = __shfl_xor(bi, m);
            if (ov > bv || (ov == bv && oi < bi)) { bv = ov; bi = oi; }
        }
        const int a = bi;

        if (valid) {
            float* dst = sS + a * PST + k * 4;
#pragma unroll
            for (int j = 0; j < 12; ++j) {
                atomicAdd(dst + j * 64 + 0, xa[j].x * rn);
                atomicAdd(dst + j * 64 + 1, xa[j].y * rn);
                atomicAdd(dst + j * 64 + 2, xa[j].z * rn);
                atomicAdd(dst + j * 64 + 3, xa[j].w * rn);
            }
            if (k == 0) atomicAdd(&sC[a], 1.0f);
        }
    }

    __syncthreads();
    // flush block partials to global accumulators (native f32 atomics, device scope)
    for (int i = tid; i < NP * D; i += 1024) {
        const int p = i / D;
        const int dd = i - p * D;
        __hip_atomic_fetch_add(&gsum[i], sS[p * PST + dd], __ATOMIC_RELAXED,
                               __HIP_MEMORY_SCOPE_AGENT);
    }
    if (tid < NP)
        __hip_atomic_fetch_add(&gcnt[tid], sC[tid], __ATOMIC_RELAXED,
                               __HIP_MEMORY_SCOPE_AGENT);
}

__global__ __launch_bounds__(256) void finalize_kernel(const float* __restrict__ ws,
                                                       float* __restrict__ out) {
    const int i = blockIdx.x * blockDim.x + threadIdx.x;
    if (i < NP * D) {
        const int p = i / D;
        const float c = ws[24576 + p];
        const float s = ws[12288 + i];
        out[i] = (c > 0.f) ? s / fmaxf(c, 1.0f) : 0.f;
    }
}

extern "C" void kernel_launch(void* const* d_in, const int* in_sizes, int n_in,
                              void* d_out, int out_size, void* d_ws, size_t ws_size,
                              hipStream_t stream) {
    const float* x = (const float*)d_in[0];
    const float* protos = (const float*)d_in[1];
    float* ws = (float*)d_ws;
    float* out = (float*)d_out;
    const int nrows = in_sizes[0] / D;  // 200000

    setup_kernel<<<16, 64, 0, stream>>>(protos, ws);
    assign_accum_kernel<<<256, 1024, 0, stream>>>(x, ws, ws + 12288, ws + 24576, nrows);
    finalize_kernel<<<(NP * D + 255) / 256, 256, 0, stream>>>(ws, out);
}

// Round 3
// 1004.450 us; speedup vs baseline: 1.1397x; 1.1397x over previous
//
#include <hip/hip_runtime.h>

#define NP 16
#define D 768
#define SUMST 769   // odd stride: scatter bank = (proto + col) % 32, spreads classes
#define TSTR 36     // tile stride in floats: 144 B (16B-aligned for b128), 2-way banks (free)
#define NWAVES 8
#define NBLK 256
#define NCHUNK 24   // D / 32

// ws layout (floats):
// [0, 12288)      PT: transposed, row-normalized prototypes, PT[j][p] = P[p][j]/||P[p]||
// [12288, 24576)  global sums accumulator
// [24576, 24592)  global counts accumulator

__global__ __launch_bounds__(64) void setup_kernel(const float* __restrict__ protos,
                                                   float* __restrict__ ws) {
    const int p = blockIdx.x;     // 0..15
    const int lane = threadIdx.x; // 0..63

    float* gsum = ws + 12288 + p * D;
    for (int j = lane; j < D; j += 64) gsum[j] = 0.f;
    if (lane == 0) ws[24576 + p] = 0.f;

    const float* pr = protos + p * D;
    float v[12];
    float ns = 0.f;
#pragma unroll
    for (int j = 0; j < 12; ++j) {
        v[j] = pr[lane + 64 * j];
        ns = fmaf(v[j], v[j], ns);
    }
#pragma unroll
    for (int m = 1; m < 64; m <<= 1) ns += __shfl_xor(ns, m);
    const float rn = 1.0f / sqrtf(ns);
#pragma unroll
    for (int j = 0; j < 12; ++j) ws[(lane + 64 * j) * NP + p] = v[j] * rn;  // PT[j][p]
}

__global__ __launch_bounds__(512) void fused_kernel(const float* __restrict__ x,
                                                    const float* __restrict__ ws,
                                                    float* __restrict__ gsum,
                                                    float* __restrict__ gcnt,
                                                    int nrows, int rpw) {
    __shared__ float sS[NP * SUMST];              // 49.2 KB block-level segment sums
    __shared__ float sC[NP];
    __shared__ float tile[NWAVES][64][TSTR];      // 73.7 KB wave-private transpose tiles

    const int tid = threadIdx.x;
    for (int i = tid; i < NP * SUMST; i += 512) sS[i] = 0.f;
    if (tid < NP) sC[tid] = 0.f;
    __syncthreads();

    const int wave = tid >> 6;
    const int lane = tid & 63;
    float(*T)[TSTR] = tile[wave];
    const int lr = lane >> 3;        // load sub-row: this lane covers rows lr, lr+8, ..., lr+56
    const int lc = (lane & 7) << 2;  // load col within 32-col chunk
    const float* pt = ws;            // PT[j][p]

    const int wbase = (blockIdx.x * NWAVES + wave) * rpw;  // this wave's consecutive row range

    for (int base = wbase; base < wbase + rpw; base += 64) {
        const int rem = wbase + rpw - base;
        const int cnt = rem < 64 ? rem : 64;

        // clamped row base pointers for the cooperative tile loads (8 rows per lane)
        const float* rowp[8];
#pragma unroll
        for (int s = 0; s < 8; ++s) {
            int rr = base + lr + 8 * s;
            rr = rr < nrows ? rr : nrows - 1;
            rowp[s] = x + (size_t)rr * D + lc;
        }

        // ================= phase A: dots + norm + argmax =================
        float4 pre[8];
#pragma unroll
        for (int s = 0; s < 8; ++s) pre[s] = *(const float4*)(rowp[s]);

        float dacc[NP];
#pragma unroll
        for (int p = 0; p < NP; ++p) dacc[p] = 0.f;
        float ns = 0.f;

        for (int c = 0; c < NCHUNK; ++c) {
            // stage chunk c into the wave-private tile (coalesced 128B-line global loads)
#pragma unroll
            for (int s = 0; s < 8; ++s) *(float4*)&T[lr + 8 * s][lc] = pre[s];
            if (c + 1 < NCHUNK) {
#pragma unroll
                for (int s = 0; s < 8; ++s) pre[s] = *(const float4*)(rowp[s] + (c + 1) * 32);
            }
            // consume: each lane reads its own row; protos via scalar loads (uniform idx)
#pragma unroll
            for (int g = 0; g < 8; ++g) {
                const float4 xv = *(const float4*)&T[lane][g * 4];
                const float* pp = pt + (c * 32 + g * 4) * NP;
                ns = fmaf(xv.x, xv.x, ns);
#pragma unroll
                for (int p = 0; p < NP; ++p) dacc[p] = fmaf(xv.x, pp[p], dacc[p]);
                ns = fmaf(xv.y, xv.y, ns);
#pragma unroll
                for (int p = 0; p < NP; ++p) dacc[p] = fmaf(xv.y, pp[NP + p], dacc[p]);
                ns = fmaf(xv.z, xv.z, ns);
#pragma unroll
                for (int p = 0; p < NP; ++p) dacc[p] = fmaf(xv.z, pp[2 * NP + p], dacc[p]);
                ns = fmaf(xv.w, xv.w, ns);
#pragma unroll
                for (int p = 0; p < NP; ++p) dacc[p] = fmaf(xv.w, pp[3 * NP + p], dacc[p]);
            }
        }

        // lane-local argmax (strict > keeps first index == argmin(dist) semantics)
        int a = 0;
        float bv = dacc[0];
#pragma unroll
        for (int p = 1; p < NP; ++p)
            if (dacc[p] > bv) { bv = dacc[p]; a = p; }
        const float rn = 1.0f / sqrtf(ns);
        const bool valid = (lane < cnt) && (base + lane < nrows);

        // ================= phase B: re-stream row, scatter into block sums =================
#pragma unroll
        for (int s = 0; s < 8; ++s) pre[s] = *(const float4*)(rowp[s]);
        float* dstS = sS + a * SUMST;

        for (int c = 0; c < NCHUNK; ++c) {
#pragma unroll
            for (int s = 0; s < 8; ++s) *(float4*)&T[lr + 8 * s][lc] = pre[s];
            if (c + 1 < NCHUNK) {
#pragma unroll
                for (int s = 0; s < 8; ++s) pre[s] = *(const float4*)(rowp[s] + (c + 1) * 32);
            }
#pragma unroll
            for (int g = 0; g < 8; ++g) {
                const float4 xv = *(const float4*)&T[lane][g * 4];
                if (valid) {
                    const int col = c * 32 + g * 4;
                    atomicAdd(&dstS[col + 0], xv.x * rn);
                    atomicAdd(&dstS[col + 1], xv.y * rn);
                    atomicAdd(&dstS[col + 2], xv.z * rn);
                    atomicAdd(&dstS[col + 3], xv.w * rn);
                }
            }
        }
        if (valid) atomicAdd(&sC[a], 1.0f);
    }

    __syncthreads();
    // flush block partials to global accumulators
    for (int i = tid; i < NP * D; i += 512) {
        const int p = i / D;
        const int dd = i - p * D;
        __hip_atomic_fetch_add(&gsum[i], sS[p * SUMST + dd], __ATOMIC_RELAXED,
                               __HIP_MEMORY_SCOPE_AGENT);
    }
    if (tid < NP)
        __hip_atomic_fetch_add(&gcnt[tid], sC[tid], __ATOMIC_RELAXED,
                               __HIP_MEMORY_SCOPE_AGENT);
}

__global__ __launch_bounds__(256) void finalize_kernel(const float* __restrict__ ws,
                                                       float* __restrict__ out) {
    const int i = blockIdx.x * blockDim.x + threadIdx.x;
    if (i < NP * D) {
        const int p = i / D;
        const float c = ws[24576 + p];
        const float s = ws[12288 + i];
        out[i] = (c > 0.f) ? s / fmaxf(c, 1.0f) : 0.f;
    }
}

extern "C" void kernel_launch(void* const* d_in, const int* in_sizes, int n_in,
                              void* d_out, int out_size, void* d_ws, size_t ws_size,
                              hipStream_t stream) {
    const float* x = (const float*)d_in[0];
    const float* protos = (const float*)d_in[1];
    float* ws = (float*)d_ws;
    float* out = (float*)d_out;
    const int nrows = in_sizes[0] / D;                       // 200000
    const int rpw = (nrows + NBLK * NWAVES - 1) / (NBLK * NWAVES);  // rows per wave (98)

    setup_kernel<<<16, 64, 0, stream>>>(protos, ws);
    fused_kernel<<<NBLK, 512, 0, stream>>>(x, ws, ws + 12288, ws + 24576, nrows, rpw);
    finalize_kernel<<<(NP * D + 255) / 256, 256, 0, stream>>>(ws, out);
}

// Round 4
// 468.159 us; speedup vs baseline: 2.4452x; 2.1455x over previous
//
#include <hip/hip_runtime.h>

#define NP 16
#define D 768
#define CCH 128  // cols per chunk in accumulate kernel

// ws float layout:
//  [0, 12288)        PT[col][p]  (transposed, row-normalized prototypes)
//  [12288, 24576)    gsum[16][768]
//  [24576, 24592)    gcnt[16]
//  [24592, 24592+N)  rn[N]
//  int32 assign[N] immediately after rn

__global__ __launch_bounds__(64) void setup_kernel(const float* __restrict__ protos,
                                                   float* __restrict__ ws) {
    const int p = blockIdx.x;     // 0..15
    const int lane = threadIdx.x; // 0..63
    float* gsum = ws + 12288 + p * D;
    for (int j = lane; j < D; j += 64) gsum[j] = 0.f;
    if (lane == 0) ws[24576 + p] = 0.f;
    const float* pr = protos + p * D;
    float v[12];
    float ns = 0.f;
#pragma unroll
    for (int j = 0; j < 12; ++j) {
        v[j] = pr[lane + 64 * j];
        ns = fmaf(v[j], v[j], ns);
    }
#pragma unroll
    for (int m = 1; m < 64; m <<= 1) ns += __shfl_xor(ns, m);
    const float rn = 1.0f / sqrtf(ns);
#pragma unroll
    for (int j = 0; j < 12; ++j) ws[(lane + 64 * j) * NP + p] = v[j] * rn;  // PT[col][p]
}

// One lane per row. Per 32-col chunk: coalesced stage (full 128B lines) into a
// wave-private LDS tile, then each lane consumes its own row's 32 cols.
// Prototypes fetched with provably-uniform addresses -> scalar loads (SGPRs).
__global__ __launch_bounds__(256) void assign_kernel(const float* __restrict__ x,
                                                     const float* __restrict__ pt,
                                                     float* __restrict__ rnout,
                                                     int* __restrict__ aout, int nrows) {
    __shared__ float tile[4][64][33];  // 33.8 KB, wave-private slices, no barriers
    const int tid = threadIdx.x;
    const int w = tid >> 6, lane = tid & 63;
    float(*T)[33] = tile[w];
    const int rowbase = blockIdx.x * 256 + w * 64;
    const int lr = lane >> 3;        // 0..7: sub-row for staging
    const int lc = (lane & 7) * 4;   // float col (8 lanes x 16B = one full line)

    float dacc[NP];
#pragma unroll
    for (int p = 0; p < NP; ++p) dacc[p] = 0.f;
    float ns = 0.f;

    const float* xb = x + (size_t)(rowbase + lr) * D + lc;

    for (int ch = 0; ch < 24; ++ch) {
        // stage 64 rows x 32 cols (transient regs only; predicated tail)
#pragma unroll
        for (int s = 0; s < 8; ++s) {
            if (rowbase + lr + 8 * s < nrows) {
                const float4 v = *(const float4*)(xb + (size_t)(8 * s) * D + ch * 32);
                *(float4*)&T[lr + 8 * s][lc] = v;
            }
        }
        asm volatile("" ::: "memory");  // keep ds_read after ds_write (per-wave DS FIFO does the rest)

        const float* pp = pt + ch * 32 * NP;  // uniform: arg + loop constants -> s_load
#pragma unroll
        for (int q = 0; q < 8; ++q) {
            const float4 xq = *(const float4*)&T[lane][q * 4];
            {
                const float xc = xq.x; ns = fmaf(xc, xc, ns);
#pragma unroll
                for (int p = 0; p < NP; ++p) dacc[p] = fmaf(pp[(q * 4 + 0) * NP + p], xc, dacc[p]);
            }
            {
                const float xc = xq.y; ns = fmaf(xc, xc, ns);
#pragma unroll
                for (int p = 0; p < NP; ++p) dacc[p] = fmaf(pp[(q * 4 + 1) * NP + p], xc, dacc[p]);
            }
            {
                const float xc = xq.z; ns = fmaf(xc, xc, ns);
#pragma unroll
                for (int p = 0; p < NP; ++p) dacc[p] = fmaf(pp[(q * 4 + 2) * NP + p], xc, dacc[p]);
            }
            {
                const float xc = xq.w; ns = fmaf(xc, xc, ns);
#pragma unroll
                for (int p = 0; p < NP; ++p) dacc[p] = fmaf(pp[(q * 4 + 3) * NP + p], xc, dacc[p]);
            }
        }
        asm volatile("" ::: "memory");  // reads done before next chunk overwrites tile
    }

    // lane-local argmax; strict > keeps first index == argmin(dist) semantics
    int a = 0;
    float bv = dacc[0];
#pragma unroll
    for (int p = 1; p < NP; ++p)
        if (dacc[p] > bv) { bv = dacc[p]; a = p; }
    const float rn = 1.0f / sqrtf(ns);
    const int row = rowbase + lane;
    if (row < nrows) {
        rnout[row] = rn;
        aout[row] = a;
    }
}

// grid (6 col-chunks, 192 row-blocks); coalesced float2 reads; wave-private
// LDS sums (non-atomic, conflict-free); one global-atomic flush per block.
__global__ __launch_bounds__(256) void accum_kernel(const float* __restrict__ x,
                                                    const float* __restrict__ rnarr,
                                                    const int* __restrict__ aarr,
                                                    float* __restrict__ gsum,
                                                    float* __restrict__ gcnt,
                                                    int nrows, int rpb) {
    __shared__ float S[4][NP][CCH];  // 32 KB
    __shared__ float C[4][NP];
    const int tid = threadIdx.x, w = tid >> 6, lane = tid & 63;
    const int chunk = blockIdx.x;  // 0..5
    const int rb = blockIdx.y * rpb;

    for (int i = tid; i < 4 * NP * CCH; i += 256) ((float*)S)[i] = 0.f;
    if (tid < 4 * NP) ((float*)C)[tid] = 0.f;
    __syncthreads();

    const int cbase = chunk * CCH + lane * 2;
    const int rend = min(rb + rpb, nrows);
    for (int r = rb + w; r < rend; r += 4) {
        const float2 xv = *(const float2*)(x + (size_t)r * D + cbase);
        const float rn = rnarr[r];  // uniform -> s_load
        const int a = aarr[r];      // uniform -> s_load
        float* s = &S[w][a][lane * 2];
        s[0] = fmaf(xv.x, rn, s[0]);
        s[1] = fmaf(xv.y, rn, s[1]);
        if (chunk == 0 && lane == 0) C[w][a] += 1.f;
    }
    __syncthreads();

    for (int i = tid; i < NP * CCH; i += 256) {
        const int p = i / CCH, c = i - p * CCH;
        const float v = S[0][p][c] + S[1][p][c] + S[2][p][c] + S[3][p][c];
        __hip_atomic_fetch_add(&gsum[p * D + chunk * CCH + c], v, __ATOMIC_RELAXED,
                               __HIP_MEMORY_SCOPE_AGENT);
    }
    if (chunk == 0 && tid < NP) {
        const float v = C[0][tid] + C[1][tid] + C[2][tid] + C[3][tid];
        __hip_atomic_fetch_add(&gcnt[tid], v, __ATOMIC_RELAXED, __HIP_MEMORY_SCOPE_AGENT);
    }
}

__global__ __launch_bounds__(256) void finalize_kernel(const float* __restrict__ ws,
                                                       float* __restrict__ out) {
    const int i = blockIdx.x * blockDim.x + threadIdx.x;
    if (i < NP * D) {
        const int p = i / D;
        const float c = ws[24576 + p];
        const float s = ws[12288 + i];
        out[i] = (c > 0.f) ? s / fmaxf(c, 1.0f) : 0.f;
    }
}

extern "C" void kernel_launch(void* const* d_in, const int* in_sizes, int n_in,
                              void* d_out, int out_size, void* d_ws, size_t ws_size,
                              hipStream_t stream) {
    const float* x = (const float*)d_in[0];
    const float* protos = (const float*)d_in[1];
    float* ws = (float*)d_ws;
    float* out = (float*)d_out;
    const int nrows = in_sizes[0] / D;  // 200000

    float* rnarr = ws + 24592;
    int* aarr = (int*)(ws + 24592 + nrows);
    const int rpb = (nrows + 191) / 192;  // rows per accumulate block

    setup_kernel<<<16, 64, 0, stream>>>(protos, ws);
    assign_kernel<<<(nrows + 255) / 256, 256, 0, stream>>>(x, ws, rnarr, aarr, nrows);
    accum_kernel<<<dim3(6, 192), 256, 0, stream>>>(x, rnarr, aarr, ws + 12288, ws + 24576,
                                                   nrows, rpb);
    finalize_kernel<<<(NP * D + 255) / 256, 256, 0, stream>>>(ws, out);
}